// Round 3
// baseline (622.055 us; speedup 1.0000x reference)
//
#include <hip/hip_runtime.h>

// Problem constants (from reference)
#define C_IN  8
#define H     32
#define W     32
#define C_OUT 16
#define KH    3
#define KW    3
#define OH    32
#define OW    32
#define N_IN  (C_IN * H * W)     // 8192
#define N_OUT (C_OUT * OH * OW)  // 16384
#define MROWS (N_IN + 1)         // 8193
#define MCOLS (N_OUT + 1)        // 16385

typedef float v4f __attribute__((ext_vector_type(4)));

// Grid layout (single dispatch):
//   b == 0           : bias row (row 8192)
//   b in [1, 65)     : interval bounds lo/hi (64 blocks)
//   b in [65, 8257)  : one block per M-row: nt zero-fill, barrier, scatter.
//
// Round-0 vs round-2 lesson: screened fill and clean fill+scatter time
// IDENTICALLY (544.0 vs 544.3) -> the M store stream is capped at ~2.7 TB/s
// by the store path, not by inner-loop arithmetic. The rocclr fill hits
// 6.2 TB/s on the same region. This round's single change: nontemporal
// (evict-first) stores for all bulk writes. nt is a replacement hint on
// CDNA (coherent through L2), so the compiler's vmcnt(0)-before-s_barrier
// at __syncthreads still orders the later scatter overwrites.
#define NB_PRE   65
#define NB_ROWS  8192

__global__ __launch_bounds__(256) void fused_kernel(const float* __restrict__ l_in,
                                                    const float* __restrict__ u_in,
                                                    const float* __restrict__ wts,
                                                    const float* __restrict__ bias,
                                                    float* __restrict__ out,
                                                    float* __restrict__ M) {
    const int b = blockIdx.x;
    const int t = threadIdx.x;

    if (b >= NB_PRE) {
        // ---------------- row fill + in-block scatter ----------------
        const int r = b - NB_PRE;                       // 0..8191
        const size_t base = (size_t)r * MCOLS;          // word index of row start
        float* __restrict__ rowp = M + base;

        // --- pre-compute this thread's nonzero (if any); load weight early so
        //     its latency hides under the fill stores ---
        const int iy  = (r >> 5) & 31;
        const int ix  = r & 31;
        const int cin = r >> 10;
        bool   ok = false;
        float  wv = 0.0f;
        int    col = 0;
        if (t < 144) {
            const int oc = t / 9;                       // 0..15
            const int q  = t - oc * 9;                  // 0..8
            const int di = q / 3;
            const int dj = q - di * 3;
            const int i  = iy - 1 + di;                 // output row
            const int j  = ix - 1 + dj;                 // output col
            ok = ((unsigned)i < 32u) & ((unsigned)j < 32u);
            if (ok) {
                const int kh = 2 - di;
                const int kw = 2 - dj;
                wv  = wts[oc * 72 + cin * 9 + kh * 3 + kw];
                col = (oc << 10) + (i << 5) + j;
            }
        }

        // --- step 1: nt zero-fill the row (16385 words; head/body/tail for
        //     16B alignment: row start drifts by r mod 4 words) ---
        const int mis = (int)(base & 3);
        const int a   = (4 - mis) & 3;                  // head words
        if (t < a) __builtin_nontemporal_store(0.0f, rowp + t);

        const int nwords = MCOLS - a;                   // 16382..16385
        const int nspans = nwords >> 2;                 // 4095 or 4096
        const int ntail  = nwords & 3;
        float* __restrict__ bodyp = rowp + a;           // 16B aligned
        const v4f zero = {0.0f, 0.0f, 0.0f, 0.0f};

        // 15 always-valid spans per thread + 1 predicated (nspans >= 4095,
        // t + 14*256 <= 3839 < 4095 always valid).
        #pragma unroll
        for (int k = 0; k < 15; ++k)
            __builtin_nontemporal_store(zero, (v4f*)(bodyp + 4 * (t + 256 * k)));
        if (t + 3840 < nspans)
            __builtin_nontemporal_store(zero, (v4f*)(bodyp + 4 * (t + 3840)));

        if (t < ntail) __builtin_nontemporal_store(0.0f, bodyp + 4 * nspans + t);

        __syncthreads();

        // --- step 2: scatter the nonzeros (regular cached stores) ---
        if (ok) rowp[col] = wv;
        return;
    }

    if (b == 0) {
        // ---------------- bias row (row 8192; word base is 16B aligned) -----
        float* __restrict__ Mrow = M + (size_t)N_IN * MCOLS;
        #pragma unroll
        for (int k = 0; k < 16; ++k) {
            const float bv = bias[k];                   // word (k<<10)+4t -> channel k
            v4f v = {bv, bv, bv, bv};
            __builtin_nontemporal_store(v, (v4f*)(Mrow + (k << 10) + 4 * t));
        }
        if (t == 0) Mrow[N_OUT] = 1.0f;
        return;
    }

    // ---------------- interval bounds (unchanged, verified) ----------------
    int tid = (b - 1) * 256 + t;
    int c = tid >> 10;
    int i = (tid >> 5) & 31;
    int j = tid & 31;

    float lo = bias[c];
    float hi = lo;

    #pragma unroll
    for (int cin = 0; cin < C_IN; ++cin) {
        #pragma unroll
        for (int kh = 0; kh < KH; ++kh) {
            int iy = i - 1 + kh;
            if ((unsigned)iy >= (unsigned)H) continue;
            #pragma unroll
            for (int kw = 0; kw < KW; ++kw) {
                int ix = j - 1 + kw;
                if ((unsigned)ix >= (unsigned)W) continue;
                float w = wts[c * 72 + cin * 9 + kh * 3 + kw];
                int   r = cin * 1024 + iy * 32 + ix;
                float a  = w * l_in[r];
                float bb = w * u_in[r];
                lo += fminf(a, bb);
                hi += fmaxf(a, bb);
            }
        }
    }
    out[tid]         = lo;
    out[N_OUT + tid] = hi;
}

extern "C" void kernel_launch(void* const* d_in, const int* in_sizes, int n_in,
                              void* d_out, int out_size, void* d_ws, size_t ws_size,
                              hipStream_t stream) {
    const float* lower = (const float*)d_in[0];
    const float* upper = (const float*)d_in[1];
    const float* wts   = (const float*)d_in[2];
    const float* bias  = (const float*)d_in[3];

    float* out = (float*)d_out;
    float* M   = out + 2 * N_OUT;   // lo(16384) | hi(16384) | M(8193*16385)

    const int grid = NB_PRE + NB_ROWS;   // 65 + 8192 = 8257
    hipLaunchKernelGGL(fused_kernel, dim3(grid), dim3(256), 0, stream,
                       lower, upper, wts, bias, out, M);
}

// Round 4
// 546.895 us; speedup vs baseline: 1.1374x; 1.1374x over previous
//
#include <hip/hip_runtime.h>

// Problem constants (from reference)
#define C_IN  8
#define H     32
#define W     32
#define C_OUT 16
#define KH    3
#define KW    3
#define OH    32
#define OW    32
#define N_IN  (C_IN * H * W)     // 8192
#define N_OUT (C_OUT * OH * OW)  // 16384
#define MROWS (N_IN + 1)         // 8193
#define MCOLS (N_OUT + 1)        // 16385

typedef float v4f __attribute__((ext_vector_type(4)));

// FINAL KERNEL — reverted to the round-2 structure (nt stores removed).
//
// Roofline argument (rounds 0-3): the timed graph is end-to-end HBM-write
// bound: poison fill 2.148 GB (harness) + M 0.537 GB (problem) = 2.685 GB
// per iteration at ~5.3 TB/s sustained write ≈ 507 µs + ~40 µs of graph-node
// overhead ≈ 545 µs ≈ measured 544. Three independent M-writers (screened
// sweep r0, row-fill+scatter r2, rocclr memset r1) converge to this total;
// only pessimizations (separate cold scatter +36, nt stores +78) move it.
// M must be written in full (poison != 0), so the byte floor is fixed.
//
// Grid layout (single dispatch):
//   b == 0           : bias row (row 8192)
//   b in [1, 65)     : interval bounds lo/hi (64 blocks)
//   b in [65, 8257)  : one block per M-row: v4f zero-fill, barrier, scatter
//                      (scatter lands on lines still dirty in this XCD's L2
//                       -> no HBM read-modify-write, no extra dispatch).
#define NB_PRE   65
#define NB_ROWS  8192

__global__ __launch_bounds__(256) void fused_kernel(const float* __restrict__ l_in,
                                                    const float* __restrict__ u_in,
                                                    const float* __restrict__ wts,
                                                    const float* __restrict__ bias,
                                                    float* __restrict__ out,
                                                    float* __restrict__ M) {
    const int b = blockIdx.x;
    const int t = threadIdx.x;

    if (b >= NB_PRE) {
        // ---------------- row fill + in-block scatter ----------------
        const int r = b - NB_PRE;                       // 0..8191
        const size_t base = (size_t)r * MCOLS;          // word index of row start
        float* __restrict__ rowp = M + base;

        // pre-compute this thread's nonzero (if any); weight load issued early
        // so its latency hides under the fill stores
        const int iy  = (r >> 5) & 31;
        const int ix  = r & 31;
        const int cin = r >> 10;
        bool   ok = false;
        float  wv = 0.0f;
        int    col = 0;
        if (t < 144) {
            const int oc = t / 9;                       // 0..15
            const int q  = t - oc * 9;                  // 0..8
            const int di = q / 3;
            const int dj = q - di * 3;
            const int i  = iy - 1 + di;                 // output row
            const int j  = ix - 1 + dj;                 // output col
            ok = ((unsigned)i < 32u) & ((unsigned)j < 32u);
            if (ok) {
                const int kh = 2 - di;
                const int kw = 2 - dj;
                wv  = wts[oc * 72 + cin * 9 + kh * 3 + kw];
                col = (oc << 10) + (i << 5) + j;
            }
        }

        // step 1: zero-fill the row (16385 words; head/body/tail because the
        // row start drifts by r mod 4 words)
        const int mis = (int)(base & 3);
        const int a   = (4 - mis) & 3;                  // head words
        if (t < a) rowp[t] = 0.0f;

        const int nwords = MCOLS - a;                   // 16382..16385
        const int nspans = nwords >> 2;                 // 4095 or 4096
        const int ntail  = nwords & 3;
        float* __restrict__ bodyp = rowp + a;           // 16B aligned
        const v4f zero = {0.0f, 0.0f, 0.0f, 0.0f};

        // 15 always-valid spans per thread + 1 predicated (nspans >= 4095,
        // t + 14*256 <= 3839 < 4095 always valid).
        #pragma unroll
        for (int k = 0; k < 15; ++k)
            *(v4f*)(bodyp + 4 * (t + 256 * k)) = zero;
        if (t + 3840 < nspans)
            *(v4f*)(bodyp + 4 * (t + 3840)) = zero;

        if (t < ntail) bodyp[4 * nspans + t] = 0.0f;

        __syncthreads();

        // step 2: scatter the nonzeros (L2-hot lines)
        if (ok) rowp[col] = wv;
        return;
    }

    if (b == 0) {
        // ---------------- bias row (row 8192; word base is 16B aligned) -----
        float* __restrict__ Mrow = M + (size_t)N_IN * MCOLS;
        #pragma unroll
        for (int k = 0; k < 16; ++k) {
            const float bv = bias[k];                   // word (k<<10)+4t -> channel k
            v4f v = {bv, bv, bv, bv};
            *(v4f*)(Mrow + (k << 10) + 4 * t) = v;
        }
        if (t == 0) Mrow[N_OUT] = 1.0f;
        return;
    }

    // ---------------- interval bounds (verified) ----------------
    int tid = (b - 1) * 256 + t;
    int c = tid >> 10;
    int i = (tid >> 5) & 31;
    int j = tid & 31;

    float lo = bias[c];
    float hi = lo;

    #pragma unroll
    for (int cin = 0; cin < C_IN; ++cin) {
        #pragma unroll
        for (int kh = 0; kh < KH; ++kh) {
            int iy = i - 1 + kh;
            if ((unsigned)iy >= (unsigned)H) continue;
            #pragma unroll
            for (int kw = 0; kw < KW; ++kw) {
                int ix = j - 1 + kw;
                if ((unsigned)ix >= (unsigned)W) continue;
                float w = wts[c * 72 + cin * 9 + kh * 3 + kw];
                int   r = cin * 1024 + iy * 32 + ix;
                float a  = w * l_in[r];
                float bb = w * u_in[r];
                lo += fminf(a, bb);
                hi += fmaxf(a, bb);
            }
        }
    }
    out[tid]         = lo;
    out[N_OUT + tid] = hi;
}

extern "C" void kernel_launch(void* const* d_in, const int* in_sizes, int n_in,
                              void* d_out, int out_size, void* d_ws, size_t ws_size,
                              hipStream_t stream) {
    const float* lower = (const float*)d_in[0];
    const float* upper = (const float*)d_in[1];
    const float* wts   = (const float*)d_in[2];
    const float* bias  = (const float*)d_in[3];

    float* out = (float*)d_out;
    float* M   = out + 2 * N_OUT;   // lo(16384) | hi(16384) | M(8193*16385)

    const int grid = NB_PRE + NB_ROWS;   // 65 + 8192 = 8257
    hipLaunchKernelGGL(fused_kernel, dim3(grid), dim3(256), 0, stream,
                       lower, upper, wts, bias, out, M);
}